// Round 13
// baseline (81.674 us; speedup 1.0000x reference)
//
#include <hip/hip_runtime.h>
#include <math.h>

// GptOssRouter: T=16384, H=2880, E=128, K=4.
// K0: pre-split w (fp32 -> bf16 h/l, trunc-exact) into d_ws as 32-k MFMA
//     B-fragment tiles: tile(F,c32,p)[lane] = 8 bf16 of
//     w[F*16+(lane&15)][c32*32+(lane>>4)*8 ...].
// K1 (fused): 32 tokens x 128 experts per block, grid=512 (2 blocks/CU).
//     K-SPLIT ACROSS WAVES: 8 waves = (K-half kt) x (expert-group wn).
//     Each wave: 32x32 tile over its 1440-k half, 15 chunks of KC=96,
//     ping-pong LDS x buffers (2 halves x 2 bufs x 16KB = 64KB), x loads 2
//     phases ahead in regs, w frags global->VGPR. 16 waves/CU occupancy.
//     3-pass split-bf16 MFMA: xh*wh + xh*wl + xl*wh (err ~1e-5); cross-half
//     fp32 reduction via LDS; fused stripe-top8 + certified-gap (TAU=2.5e-4):
//     fast fp32 softmax; rare fp64 rescore (order == float64 numpy ref).

#define T_TOK 16384
#define HDIM  2880
#define EEXP  128
#define KTOP  4

#define TM    32
#define NT    512
#define KCH   96             // floats per chunk per half
#define NPH   15             // chunks per half
#define HALFK 1440
#define TAU   2.5e-4f

typedef __attribute__((ext_vector_type(8))) short bf16x8;
typedef __attribute__((ext_vector_type(4))) float f32x4;

#define MFMA(a, b, c) __builtin_amdgcn_mfma_f32_16x16x32_bf16((a), (b), (c), 0, 0, 0)

// ---------------- K0: w pre-split into 32-k fragment tiles ------------------
__global__ __launch_bounds__(256) void w_split(
    const float* __restrict__ w, char* __restrict__ wp)
{
    const int gid  = blockIdx.x * 256 + threadIdx.x;   // 46080 = 720 tiles * 64
    const int lane = gid & 63;
    const int q    = gid >> 6;        // 0..719
    const int c32  = q % 90;
    const int F    = q / 90;          // 0..7
    const int e    = F * 16 + (lane & 15);
    const int k0   = c32 * 32 + (lane >> 4) * 8;

    const float* src = w + (size_t)e * HDIM + k0;
    float4 v0 = *(const float4*)(src);
    float4 v1 = *(const float4*)(src + 4);
    float vv[8] = {v0.x, v0.y, v0.z, v0.w, v1.x, v1.y, v1.z, v1.w};
    union { unsigned short s[8]; uint4 u; } H, L;
#pragma unroll
    for (int j = 0; j < 8; ++j) {
        unsigned u = __float_as_uint(vv[j]);
        H.s[j] = (unsigned short)(u >> 16);
        float rr = vv[j] - __uint_as_float(u & 0xffff0000u);
        L.s[j] = (unsigned short)(__float_as_uint(rr) >> 16);
    }
    const int tile = (F * 90 + c32) * 2;               // h; l at +1
    *(uint4*)(wp + (size_t)tile * 1024 + lane * 16)       = H.u;
    *(uint4*)(wp + (size_t)(tile + 1) * 1024 + lane * 16) = L.u;
}

// x split: v = h + l (both trunc-bf16 exact); h 8B at swizzled slot, l at +256.
static __device__ __forceinline__ void split_write(char* base, int off, float4 v) {
    union { float4 v4; unsigned u[4]; } uv; uv.v4 = v;
    unsigned h01 = __builtin_amdgcn_perm(uv.u[1], uv.u[0], 0x07060302u);
    unsigned h23 = __builtin_amdgcn_perm(uv.u[3], uv.u[2], 0x07060302u);
    float r0 = v.x - __uint_as_float(uv.u[0] & 0xffff0000u);
    float r1 = v.y - __uint_as_float(uv.u[1] & 0xffff0000u);
    float r2 = v.z - __uint_as_float(uv.u[2] & 0xffff0000u);
    float r3 = v.w - __uint_as_float(uv.u[3] & 0xffff0000u);
    unsigned l01 = __builtin_amdgcn_perm(__float_as_uint(r1), __float_as_uint(r0), 0x07060302u);
    unsigned l23 = __builtin_amdgcn_perm(__float_as_uint(r3), __float_as_uint(r2), 0x07060302u);
    uint2 hw; hw.x = h01; hw.y = h23;
    uint2 lw; lw.x = l01; lw.y = l23;
    *(uint2*)(base + off)       = hw;
    *(uint2*)(base + off + 256) = lw;
}

// ---------------- K1: fused GEMM + selection --------------------------------
__global__ __launch_bounds__(NT, 4) void router_fused(
    const float* __restrict__ x, const char* __restrict__ wp,
    const float* __restrict__ w, const float* __restrict__ bias,
    float* __restrict__ out)
{
    __shared__ char smem[65536];
    const int tid  = threadIdx.x;
    const int tok0 = blockIdx.x * TM;
    const int lane = tid & 63;
    const int wv   = tid >> 6;          // 0..7
    const int kt   = wv >> 2;           // K half
    const int wn   = wv & 3;            // expert 32-group
    const int r    = lane & 15;
    const int g    = lane >> 4;

    // x staging map: 1536 float4 per chunk-pair phase? -> per phase each half
    // stages 768 float4; thread handles 3 (both halves mixed).
    int hoff[3];
    const float* xptr[3];
#pragma unroll
    for (int i = 0; i < 3; ++i) {
        int f    = tid + i * NT;        // 0..1535
        int half = (f >= 768) ? 1 : 0;
        int ff   = f - half * 768;
        int row  = ff / 24, c4 = ff % 24;
        int s    = c4 >> 1;
        hoff[i] = half * 32768 + row * 512 +
                  (((s ^ (row & 7)) << 4) | ((c4 & 1) << 3));
        xptr[i] = x + (size_t)(tok0 + row) * HDIM + half * HALFK + c4 * 4;
    }

    // a-frag read offsets [tokfrag][ks] (h; l at +256); add buf*16384 at use
    int aoff[2][3];
#pragma unroll
    for (int tf = 0; tf < 2; ++tf) {
        int row = tf * 16 + r;
#pragma unroll
        for (int ks = 0; ks < 3; ++ks) {
            int s = ks * 4 + g;
            aoff[tf][ks] = kt * 32768 + row * 512 + (((s ^ (row & 7)) << 4));
        }
    }

    f32x4 a00 = {0.f, 0.f, 0.f, 0.f}, a01 = a00, a10 = a00, a11 = a00;

#define LOADX(pf, cc) do {                                            \
        pf[0] = *(const float4*)(xptr[0] + (cc) * KCH);               \
        pf[1] = *(const float4*)(xptr[1] + (cc) * KCH);               \
        pf[2] = *(const float4*)(xptr[2] + (cc) * KCH); } while (0)

#define WRITEX(pf, cc) do { int bo_ = ((cc) & 1) * 16384;             \
        split_write(smem, hoff[0] + bo_, pf[0]);                      \
        split_write(smem, hoff[1] + bo_, pf[1]);                      \
        split_write(smem, hoff[2] + bo_, pf[2]); } while (0)

    // 12 w tiles for this wave's (kt, wn), chunk cc: W[ks*4 + F2*2 + p]
#define LOADW(W, cc) do {                                             \
        _Pragma("unroll")                                             \
        for (int ks_ = 0; ks_ < 3; ++ks_)                             \
        _Pragma("unroll")                                             \
        for (int F2_ = 0; F2_ < 2; ++F2_)                             \
        _Pragma("unroll")                                             \
        for (int p_ = 0; p_ < 2; ++p_) {                              \
            int c32_ = kt * 45 + (cc) * 3 + ks_;                      \
            int tile_ = ((wn * 2 + F2_) * 90 + c32_) * 2 + p_;        \
            W[ks_*4 + F2_*2 + p_] = *(const bf16x8*)(wp +             \
                (size_t)tile_ * 1024 + lane * 16);                    \
        } } while (0)

#define MFMA_CHUNK(bo, W) do {                                        \
        _Pragma("unroll")                                             \
        for (int ks_ = 0; ks_ < 3; ++ks_) {                           \
            bf16x8 ah0 = *(const bf16x8*)(smem + aoff[0][ks_] + (bo));\
            bf16x8 al0 = *(const bf16x8*)(smem + aoff[0][ks_] + (bo) + 256);\
            bf16x8 ah1 = *(const bf16x8*)(smem + aoff[1][ks_] + (bo));\
            bf16x8 al1 = *(const bf16x8*)(smem + aoff[1][ks_] + (bo) + 256);\
            bf16x8 bh0 = W[ks_*4], bl0 = W[ks_*4+1];                  \
            bf16x8 bh1 = W[ks_*4+2], bl1 = W[ks_*4+3];                \
            a00 = MFMA(ah0, bh0, a00); a01 = MFMA(ah0, bh1, a01);     \
            a10 = MFMA(ah1, bh0, a10); a11 = MFMA(ah1, bh1, a11);     \
            a00 = MFMA(ah0, bl0, a00); a01 = MFMA(ah0, bl1, a01);     \
            a10 = MFMA(ah1, bl0, a10); a11 = MFMA(ah1, bl1, a11);     \
            a00 = MFMA(al0, bh0, a00); a01 = MFMA(al0, bh1, a01);     \
            a10 = MFMA(al1, bh0, a10); a11 = MFMA(al1, bh1, a11);     \
        } } while (0)

    float4 pfA[3], pfB[3];
    bf16x8 W[12];

    // prologue: pfA=chunk0 -> buf0; pfB=chunk1; pfA reloads chunk2
    LOADX(pfA, 0); LOADX(pfB, 1);
    WRITEX(pfA, 0);
    LOADX(pfA, 2);
    __syncthreads();

    for (int c = 0; c < 14; c += 2) {
        // even phase: compute chunk c (buf0); stage c+1; load c+3
        WRITEX(pfB, c + 1);
        if (c + 3 < NPH) LOADX(pfB, c + 3);
        LOADW(W, c);
        MFMA_CHUNK(0, W);
        __syncthreads();
        // odd phase: compute chunk c+1 (buf1); stage c+2; load c+4
        WRITEX(pfA, c + 2);
        if (c + 4 < NPH) LOADX(pfA, c + 4);
        LOADW(W, c + 1);
        MFMA_CHUNK(16384, W);
        __syncthreads();
    }
    LOADW(W, 14);
    MFMA_CHUNK(0, W);                    // chunk 14 (buf0)
    __syncthreads();

    // -------- cross-half reduction: kt=1 -> LDS, kt=0 adds ------------------
    float* red = (float*)smem;           // [4][32][32]
    if (kt == 1) {
#pragma unroll
        for (int q = 0; q < 4; ++q) {
            int t0 = g * 4 + q, t1 = t0 + 16;
            red[(wn * 32 + t0) * 32 + r]      = a00[q];
            red[(wn * 32 + t0) * 32 + 16 + r] = a01[q];
            red[(wn * 32 + t1) * 32 + r]      = a10[q];
            red[(wn * 32 + t1) * 32 + 16 + r] = a11[q];
        }
    }
    __syncthreads();

    float* logitsL = (float*)(smem + 16384);   // [32][130]
    if (kt == 0) {
        const float bv0 = bias[wn * 32 + r];
        const float bv1 = bias[wn * 32 + 16 + r];
#pragma unroll
        for (int q = 0; q < 4; ++q) {
            int t0 = g * 4 + q, t1 = t0 + 16;
            int e0 = wn * 32 + r, e1 = e0 + 16;
            logitsL[t0 * 130 + e0] = a00[q] + red[(wn * 32 + t0) * 32 + r]      + bv0;
            logitsL[t0 * 130 + e1] = a01[q] + red[(wn * 32 + t0) * 32 + 16 + r] + bv1;
            logitsL[t1 * 130 + e0] = a10[q] + red[(wn * 32 + t1) * 32 + r]      + bv0;
            logitsL[t1 * 130 + e1] = a11[q] + red[(wn * 32 + t1) * 32 + 16 + r] + bv1;
        }
    }
    float*  cvf = (float*) (smem + 33024);   // [32][8]
    int*    cie = (int*)   (smem + 34048);   // [32][8]
    int*    flg = (int*)   (smem + 35072);   // [32]
    double* svd = (double*)(smem + 35200);   // [32][4]
    int*    sid = (int*)   (smem + 36224);   // [32][4]
    double* cvd = (double*)(smem + 36736);   // [8]
    __syncthreads();

    // -------- stripe top-8: threads 0-255, (t, s) scans 16 experts ----------
    if (tid < 256) {
        const int t = tid >> 3, s = tid & 7;
        float v[8]; int id[8];
#pragma unroll
        for (int k = 0; k < 8; ++k) { v[k] = -3.4e38f; id[k] = 0x7fffffff; }
        for (int jj = 0; jj < 16; ++jj) {
            float lv = logitsL[t * 130 + s * 16 + jj];
            int   e  = s * 16 + jj;
            bool gt[8];
#pragma unroll
            for (int k = 0; k < 8; ++k)
                gt[k] = (lv > v[k]) || (lv == v[k] && e < id[k]);
#pragma unroll
            for (int k = 7; k >= 1; --k)
                if (gt[k - 1]) { v[k] = v[k - 1]; id[k] = id[k - 1]; }
#pragma unroll
            for (int k = 0; k < 8; ++k) {
                bool put = gt[k] && (k == 0 || !gt[k - 1]);
                if (put) { v[k] = lv; id[k] = e; }
            }
        }
#pragma unroll
        for (int rd = 0; rd < 8; ++rd) {
            float hv = v[0]; int hi = id[0];
#pragma unroll
            for (int off = 1; off < 8; off <<= 1) {
                float ov = __shfl_xor(hv, off);
                int   oi = __shfl_xor(hi, off);
                if (ov > hv || (ov == hv && oi < hi)) { hv = ov; hi = oi; }
            }
            if (s == 0) { cvf[t * 8 + rd] = hv; cie[t * 8 + rd] = hi; }
            bool mine = (v[0] == hv) && (id[0] == hi);
            if (mine) {
#pragma unroll
                for (int k = 0; k < 7; ++k) { v[k] = v[k + 1]; id[k] = id[k + 1]; }
                v[7] = -3.4e38f; id[7] = 0x7fffffff;
            }
        }
    }
    __syncthreads();

    // -------- certified-gap test + fast-path fill ---------------------------
    if (tid < TM) {
        float gmin = 3.4e38f;
#pragma unroll
        for (int k = 0; k < 4; ++k)
            gmin = fminf(gmin, cvf[tid * 8 + k] - cvf[tid * 8 + k + 1]);
        flg[tid] = (gmin < TAU);
    }
    if (tid < 128) {
        int t2 = tid >> 2, k = tid & 3;
        svd[t2 * 4 + k] = (double)cvf[t2 * 8 + k];
        sid[t2 * 4 + k] = cie[t2 * 8 + k];
    }
    __syncthreads();

    // -------- rare slow path: fp64 rescore (1 candidate per wave) -----------
    for (int ts = 0; ts < TM; ++ts) {
        if (!flg[ts]) continue;              // uniform across block
        {
            const int ce = cie[ts * 8 + wv];
            const float4* xr = (const float4*)(x + (size_t)(tok0 + ts) * HDIM);
            const float4* wr = (const float4*)(w + (size_t)ce * HDIM);
            double q0 = 0.0, q1 = 0.0, q2 = 0.0, q3 = 0.0;
            for (int i2 = 0; i2 < 12; ++i2) {
                int fi = lane + i2 * 64;
                if (fi < HDIM / 4) {
                    float4 xv = xr[fi];
                    float4 wv4 = wr[fi];
                    q0 = fma((double)xv.x, (double)wv4.x, q0);
                    q1 = fma((double)xv.y, (double)wv4.y, q1);
                    q2 = fma((double)xv.z, (double)wv4.z, q2);
                    q3 = fma((double)xv.w, (double)wv4.w, q3);
                }
            }
            double accd = (q0 + q2) + (q1 + q3);
#pragma unroll
            for (int off = 32; off > 0; off >>= 1)
                accd += __shfl_xor(accd, off);
            if (lane == 0) cvd[wv] = accd + (double)bias[ce];
        }
        __syncthreads();
        if (tid < 8) {                        // fp64 rank among 8 candidates
            double mv = cvd[tid]; int mi2 = cie[ts * 8 + tid];
            int rk = 0;
#pragma unroll
            for (int j2 = 0; j2 < 8; ++j2) {
                double oj = cvd[j2];
                rk += (oj > mv) || (oj == mv && cie[ts * 8 + j2] < mi2);
            }
            if (rk < 4) { svd[ts * 4 + rk] = mv; sid[ts * 4 + rk] = mi2; }
        }
        __syncthreads();
    }

    // -------- softmax + outputs ---------------------------------------------
    float* srow = (float*)smem;              // [32][128], overlays dead red
    float4 z4 = make_float4(0.f, 0.f, 0.f, 0.f);
#pragma unroll
    for (int i = 0; i < 2; ++i)
        ((float4*)srow)[tid + i * NT] = z4;
    __syncthreads();

    if (tid < TM) {
        double m  = svd[tid * 4];
        double e0 = exp(svd[tid * 4 + 0] - m), e1 = exp(svd[tid * 4 + 1] - m);
        double e2 = exp(svd[tid * 4 + 2] - m), e3 = exp(svd[tid * 4 + 3] - m);
        double inv = 1.0 / ((e0 + e1) + (e2 + e3));
        float* oidx = out + (size_t)T_TOK * EEXP + (size_t)(tok0 + tid) * KTOP;
        int i0 = sid[tid * 4 + 0], i1 = sid[tid * 4 + 1];
        int i2 = sid[tid * 4 + 2], i3 = sid[tid * 4 + 3];
        oidx[0] = (float)i0; oidx[1] = (float)i1;
        oidx[2] = (float)i2; oidx[3] = (float)i3;
        srow[tid * EEXP + i0] = (float)(e0 * inv);
        srow[tid * EEXP + i1] = (float)(e1 * inv);
        srow[tid * EEXP + i2] = (float)(e2 * inv);
        srow[tid * EEXP + i3] = (float)(e3 * inv);
    }
    __syncthreads();

    float4* orow = (float4*)(out + (size_t)tok0 * EEXP);
#pragma unroll
    for (int i = 0; i < 2; ++i)
        orow[tid + i * NT] = ((float4*)srow)[tid + i * NT];
}

extern "C" void kernel_launch(void* const* d_in, const int* in_sizes, int n_in,
                              void* d_out, int out_size, void* d_ws, size_t ws_size,
                              hipStream_t stream) {
    const float* x    = (const float*)d_in[0];
    const float* w    = (const float*)d_in[1];
    const float* bias = (const float*)d_in[2];
    float* out        = (float*)d_out;
    char*  wp         = (char*)d_ws;   // 1440 KiB (8*90*2 tiles * 1KB)

    hipLaunchKernelGGL(w_split, dim3(180), dim3(256), 0, stream, w, wp);
    hipLaunchKernelGGL(router_fused, dim3(T_TOK / TM), dim3(NT), 0, stream,
                       x, wp, w, bias, out);
}